// Round 1
// baseline (172.234 us; speedup 1.0000x reference)
//
#include <hip/hip_runtime.h>

typedef _Float16 half8 __attribute__((ext_vector_type(8)));
typedef _Float16 half4 __attribute__((ext_vector_type(4)));
typedef float f32x4 __attribute__((ext_vector_type(4)));

#define BATCH 8
#define CH 128
#define NPIX 2304   // 48*48
#define SPLIT 4
#define JPER (NPIX / SPLIT)          // 576 = 9 tiles of 64
#define BN (BATCH * NPIX)
#define LOG2E 1.44269504088896f

__device__ __forceinline__ f32x4 mfma32(half8 a, half8 b, f32x4 c) {
    return __builtin_amdgcn_mfma_f32_16x16x32_f16(a, b, c, 0, 0, 0);
}
__device__ __forceinline__ f32x4 mfma16(half4 a, half4 b, f32x4 c) {
    return __builtin_amdgcn_mfma_f32_16x16x16f16(a, b, c, 0, 0, 0);
}

// ---------------- prep: pool (blocks 0..1023), W convert (1024..1215) ----------------
__global__ __launch_bounds__(256) void k_prep(
        const float* __restrict__ x, const float* __restrict__ Wq,
        const float* __restrict__ Wk, const float* __restrict__ Wv,
        _Float16* __restrict__ Wh, float* __restrict__ y0) {
    const int bid = blockIdx.x;
    const int t = threadIdx.x;
    if (bid < 1024) {                        // ---- global average pool
        const int row = bid;                  // b*128 + c
        const float4* p = (const float4*)(x + (size_t)row * NPIX);
        float s = 0.f;
        for (int tt = t; tt < NPIX / 4; tt += 256) {
            float4 v = p[tt];
            s += v.x + v.y + v.z + v.w;
        }
        for (int m = 1; m < 64; m <<= 1) s += __shfl_xor(s, m);
        __shared__ float ls[4];
        if ((t & 63) == 0) ls[t >> 6] = s;
        __syncthreads();
        if (t == 0) y0[row] = (ls[0] + ls[1] + ls[2] + ls[3]) * (1.0f / (float)NPIX);
    } else {                                  // ---- W f32 -> f16
        int i = (bid - 1024) * 256 + t;       // 0..49151
        const float* src = (i < 16384) ? Wq : ((i < 32768) ? Wk : Wv);
        Wh[i] = (_Float16)src[i & 16383];
    }
}

// ---------------- QKV projection (x transposed in-LDS) + SE on z==3 ----------------
// grid (18, 8, 4); block 256. z: 0=q (B,N,C), 1=k (B,N,C), 2=v (B,C,N), 3=SE
__global__ __launch_bounds__(256) void k_proj(
        const float* __restrict__ x, const _Float16* __restrict__ Wh,
        const float* __restrict__ bq, const float* __restrict__ bk, const float* __restrict__ bv,
        _Float16* __restrict__ qT, _Float16* __restrict__ kT, _Float16* __restrict__ vN,
        const float* __restrict__ y0, const float* __restrict__ se_w1,
        const float* __restrict__ se_w2, float* __restrict__ scale) {
    const int which = blockIdx.z;
    const int t = threadIdx.x;

    if (which == 3) {                         // ---- SE MLP: 1 active block
        if (blockIdx.x != 0 || blockIdx.y != 0) return;
        __shared__ float ly[128];
        __shared__ float ly1[8];
        for (int b = 0; b < BATCH; ++b) {
            if (t < 128) ly[t] = y0[b * 128 + t];
            __syncthreads();
            if (t < 8) {
                float a = 0.f;
                for (int c = 0; c < 128; ++c) a += se_w1[t * 128 + c] * ly[c];
                ly1[t] = fmaxf(a, 0.f);
            }
            __syncthreads();
            if (t < 128) {
                float a = 0.f;
                for (int r = 0; r < 8; ++r) a += se_w2[t * 8 + r] * ly1[r];
                scale[b * 128 + t] = 1.f / (1.f + __expf(-a));
            }
            __syncthreads();
        }
        return;
    }

    const int n0 = blockIdx.x * 128;
    const int b = blockIdx.y;
    const float* bias = (which == 0) ? bq : ((which == 1) ? bk : bv);
    const _Float16* W = Wh + which * 16384;

    __shared__ __align__(16) _Float16 xt[128 * 128];  // swizzled [n][c]

    { // stage x tile: f32 (C-major) -> f16 transposed swizzled [n][c]
        const float* xb = x + (size_t)b * CH * NPIX + n0;
        for (int rep = 0; rep < 16; ++rep) {
            int flat = rep * 256 + t;
            int c = flat >> 5;                // 0..127
            int n4 = (flat & 31) * 4;         // 0..124
            float4 v4 = *(const float4*)(xb + (size_t)c * NPIX + n4);
            int cc = c & 7, ck = c >> 3;
            xt[(n4 + 0) * 128 + ((ck ^ ((n4 + 0) & 7)) * 8) + cc] = (_Float16)v4.x;
            xt[(n4 + 1) * 128 + ((ck ^ ((n4 + 1) & 7)) * 8) + cc] = (_Float16)v4.y;
            xt[(n4 + 2) * 128 + ((ck ^ ((n4 + 2) & 7)) * 8) + cc] = (_Float16)v4.z;
            xt[(n4 + 3) * 128 + ((ck ^ ((n4 + 3) & 7)) * 8) + cc] = (_Float16)v4.w;
        }
    }
    __syncthreads();

    const int lane = t & 63, w = t >> 6;
    const int ln15 = lane & 15, quad = lane >> 4;

    f32x4 zero4 = {0.f, 0.f, 0.f, 0.f};
    f32x4 acc[8][2];
    for (int mt = 0; mt < 8; ++mt) { acc[mt][0] = zero4; acc[mt][1] = zero4; }

    for (int ks = 0; ks < 4; ++ks) {
        half8 bf[2];
        for (int nt = 0; nt < 2; ++nt) {
            int row = w * 32 + nt * 16 + ln15;
            int ch = ks * 4 + quad;
            bf[nt] = *(const half8*)(xt + row * 128 + ((ch ^ (row & 7)) * 8));
        }
        for (int mt = 0; mt < 8; ++mt) {
            half8 af = *(const half8*)(W + (mt * 16 + ln15) * 128 + ks * 32 + quad * 8);
            acc[mt][0] = mfma32(af, bf[0], acc[mt][0]);
            acc[mt][1] = mfma32(af, bf[1], acc[mt][1]);
        }
    }
    __syncthreads();   // xt reuse as transpose buffer

    if (which == 2) {
        // [c][n] swizzled, then coalesced store to vN (B,C,N)
        for (int mt = 0; mt < 8; ++mt)
            for (int nt = 0; nt < 2; ++nt)
                for (int r = 0; r < 4; ++r) {
                    int c = mt * 16 + quad * 4 + r;
                    int nl = w * 32 + nt * 16 + ln15;
                    xt[c * 128 + (((nl >> 3) ^ (c & 7)) * 8) + (nl & 7)] =
                        (_Float16)(acc[mt][nt][r] + bias[c]);
                }
        __syncthreads();
        _Float16* vb = vN + (size_t)b * CH * NPIX + n0;
        for (int rep = 0; rep < 8; ++rep) {
            int c = rep * 16 + (t >> 4), ch = t & 15;
            *(half8*)(vb + (size_t)c * NPIX + ch * 8) =
                *(const half8*)(xt + c * 128 + ((ch ^ (c & 7)) * 8));
        }
    } else {
        // [n][c] swizzled, then coalesced store to qT/kT (B,N,C)
        for (int mt = 0; mt < 8; ++mt)
            for (int nt = 0; nt < 2; ++nt)
                for (int r = 0; r < 4; ++r) {
                    int c = mt * 16 + quad * 4 + r;
                    int nl = w * 32 + nt * 16 + ln15;
                    xt[nl * 128 + (((c >> 3) ^ (nl & 7)) * 8) + (c & 7)] =
                        (_Float16)(acc[mt][nt][r] + bias[c]);
                }
        __syncthreads();
        _Float16* dst = ((which == 0) ? qT : kT) + ((size_t)b * NPIX + n0) * CH;
        for (int rep = 0; rep < 8; ++rep) {
            int nl = rep * 16 + (t >> 4), ch = t & 15;
            *(half8*)(dst + nl * 128 + ch * 8) =
                *(const half8*)(xt + nl * 128 + ((ch ^ (nl & 7)) * 8));
        }
    }
}

// ---------------- flash attention: async reg-staged K/V, defer-max softmax ----------------
// grid (36, 8, SPLIT); block 256. Wave w owns i-rows i0+16w..+15; all waves share K/V tile.
// T14: tile t+1 global->reg loads issue before compute of tile t; raw s_barrier (no vmcnt
// drain) keeps them in flight across the barrier. T5: setprio around MFMA clusters.
// T13: skip O-rescale when __all(mx - m <= 8); o_part stored normalized by 1/l so f16
// cannot overflow (combine weights become e_s*l_s/L).
__global__ __launch_bounds__(256, 4) void k_attn(
        const _Float16* __restrict__ qT, const _Float16* __restrict__ kT,
        const _Float16* __restrict__ vN,
        _Float16* __restrict__ o_part, float* __restrict__ g_m, float* __restrict__ g_l) {
    const int i0 = blockIdx.x * 64;
    const int b = blockIdx.y;
    const int split = blockIdx.z;
    const int t = threadIdx.x;
    const int lane = t & 63, w = t >> 6;
    const int ln15 = lane & 15, quad = lane >> 4;

    __shared__ __align__(16) _Float16 sh[16384];   // k_s = sh (64x128), v_s = sh+8192 (128x64)
    _Float16* k_s = sh;
    _Float16* v_s = sh + 8192;

    // Q frags (B-operand of S^T): i = i0 + 16w + ln15
    half8 qf[4];
    {
        const _Float16* qb = qT + ((size_t)b * NPIX + i0 + w * 16 + ln15) * CH + quad * 8;
        for (int kc = 0; kc < 4; ++kc) qf[kc] = *(const half8*)(qb + kc * 32);
    }

    // per-lane staging coordinates (constant across tiles)
    const int krow = t >> 4;          // K: row_local = r*16 + krow
    const int kch  = t & 15;
    const int vco  = t >> 3;          // V: c = r*32 + vco
    const int vch  = t & 7;
    const _Float16* kb0 = kT + ((size_t)b * NPIX) * CH;
    const _Float16* vb0 = vN + (size_t)b * CH * NPIX;

    // prologue: load tile 0 into registers (8 x 16B per lane)
    half8 kr[4], vr[4];
    {
        const int j0 = split * JPER;
        const _Float16* kb = kb0 + (size_t)(j0 + krow) * CH + kch * 8;
        for (int r = 0; r < 4; ++r) kr[r] = *(const half8*)(kb + (size_t)(r * 16) * CH);
        const _Float16* vb = vb0 + j0 + vch * 8;
        for (int r = 0; r < 4; ++r) vr[r] = *(const half8*)(vb + (size_t)(r * 32 + vco) * NPIX);
    }

    f32x4 zero4 = {0.f, 0.f, 0.f, 0.f};
    f32x4 os[8];
    for (int ct = 0; ct < 8; ++ct) os[ct] = zero4;
    float m = -1e30f, l = 0.f;

    for (int it = 0; it < 9; ++it) {
        __syncthreads();   // all readers of k_s/v_s (tile it-1) done; tile-it loads land

        { // ds_write tile it from regs (swizzled)
            for (int r = 0; r < 4; ++r) {
                int row = r * 16 + krow;
                *(half8*)(k_s + row * 128 + ((kch ^ (row & 7)) * 8)) = kr[r];
            }
            for (int r = 0; r < 4; ++r) {
                int c = r * 32 + vco;
                *(half8*)(v_s + c * 64 + ((vch ^ (c & 7)) * 8)) = vr[r];
            }
        }
        if (it < 8) { // prefetch tile it+1 into regs; latency hides under compute below
            const int j0n = split * JPER + (it + 1) * 64;
            const _Float16* kb = kb0 + (size_t)(j0n + krow) * CH + kch * 8;
            for (int r = 0; r < 4; ++r) kr[r] = *(const half8*)(kb + (size_t)(r * 16) * CH);
            const _Float16* vb = vb0 + j0n + vch * 8;
            for (int r = 0; r < 4; ++r) vr[r] = *(const half8*)(vb + (size_t)(r * 32 + vco) * NPIX);
        }
        // raw barrier: wait only LDS writes (lgkmcnt), leave prefetch vmem in flight
        asm volatile("s_waitcnt lgkmcnt(0)" ::: "memory");
        asm volatile("s_barrier" ::: "memory");

        // ---- S^T = K·Q^T : D[j = 16jt + quad*4+r][i = ln15]
        f32x4 s[4];
        for (int jt = 0; jt < 4; ++jt) s[jt] = zero4;
        __builtin_amdgcn_s_setprio(1);
        for (int jt = 0; jt < 4; ++jt) {
            for (int kc = 0; kc < 4; ++kc) {
                int row = jt * 16 + ln15, ch = kc * 4 + quad;
                half8 kf = *(const half8*)(k_s + row * 128 + ((ch ^ (row & 7)) * 8));
                s[jt] = mfma32(kf, qf[kc], s[jt]);
            }
        }
        __builtin_amdgcn_s_setprio(0);

        // ---- online softmax with deferred rescale (T13, THR=8)
        float mx = fmaxf(fmaxf(s[0][0], s[0][1]), fmaxf(s[0][2], s[0][3]));
        for (int jt = 1; jt < 4; ++jt)
            mx = fmaxf(mx, fmaxf(fmaxf(s[jt][0], s[jt][1]), fmaxf(s[jt][2], s[jt][3])));
        mx = fmaxf(mx, __shfl_xor(mx, 16));
        mx = fmaxf(mx, __shfl_xor(mx, 32));
        if (!__all(mx - m <= 8.0f)) {
            float mnew = fmaxf(m, mx);
            float alpha = exp2f((m - mnew) * LOG2E);
            for (int ct = 0; ct < 8; ++ct) {
                os[ct][0] *= alpha; os[ct][1] *= alpha;
                os[ct][2] *= alpha; os[ct][3] *= alpha;
            }
            l *= alpha;
            m = mnew;
        }
        float mbias = m * LOG2E;

        float sum = 0.f;
        half4 pf[4];
        for (int jt = 0; jt < 4; ++jt)
            for (int r = 0; r < 4; ++r) {
                float p = exp2f(fmaf(s[jt][r], LOG2E, -mbias));   // bounded by e^8
                sum += p;
                pf[jt][r] = (_Float16)p;
            }
        sum += __shfl_xor(sum, 16);
        sum += __shfl_xor(sum, 32);
        l += sum;

        // ---- O^T += V · P^T  (K=16 MFMA; P in registers, V from LDS)
        __builtin_amdgcn_s_setprio(1);
        for (int ct = 0; ct < 8; ++ct) {
            int c = ct * 16 + ln15;
            for (int jt = 0; jt < 4; ++jt) {
                int chunk = jt * 2 + (quad >> 1);
                half4 vf = *(const half4*)(v_s + c * 64 + ((chunk ^ (c & 7)) * 8) + (quad & 1) * 4);
                os[ct] = mfma16(vf, pf[jt], os[ct]);
            }
        }
        __builtin_amdgcn_s_setprio(0);
    }

    // ---- epilogue: m/l out; O^T normalized by 1/l, f16 via LDS transpose, coalesced store
    if (quad == 0) {
        int i = i0 + w * 16 + ln15;
        g_m[(size_t)(split * BATCH + b) * NPIX + i] = m;
        g_l[(size_t)(split * BATCH + b) * NPIX + i] = l;
    }
    const float linv = 1.0f / l;
    __syncthreads();   // all LDS reads done before reuse
    for (int ct = 0; ct < 8; ++ct)
        for (int r = 0; r < 4; ++r) {
            int c = ct * 16 + quad * 4 + r;
            int il = w * 16 + ln15;
            int chunk = (il >> 3);
            sh[c * 64 + ((chunk ^ (c & 7)) * 8) + (il & 7)] = (_Float16)(os[ct][r] * linv);
        }
    __syncthreads();
    _Float16* op = o_part + (size_t)(split * BATCH + b) * CH * NPIX;
    for (int rep = 0; rep < 4; ++rep) {
        int c = rep * 32 + (t >> 3), ch = t & 7;
        *(half8*)(op + (size_t)c * NPIX + i0 + ch * 8) =
            *(const half8*)(sh + c * 64 + ((ch ^ (c & 7)) * 8));
    }
}

// ---------------- combine (fused split-weights) + SE epilogue ----------------
// grid (36, 8); block 256. o_part is per-split NORMALIZED -> weight = e_s*l_s/L
__global__ __launch_bounds__(256) void k_combine(
        const _Float16* __restrict__ o_part, const float* __restrict__ g_m,
        const float* __restrict__ g_l, const float* __restrict__ x,
        const float* __restrict__ scale, const float* __restrict__ gamma_p,
        float* __restrict__ out) {
    const int i0 = blockIdx.x * 64;
    const int b = blockIdx.y;
    const int t = threadIdx.x;
    __shared__ float wl[SPLIT][64];

    if (t < 64) {
        int i = i0 + t;
        float mm[SPLIT], llv[SPLIT];
        float M = -1e30f;
        for (int s = 0; s < SPLIT; ++s) {
            mm[s] = g_m[(size_t)(s * BATCH + b) * NPIX + i];
            llv[s] = g_l[(size_t)(s * BATCH + b) * NPIX + i];
            M = fmaxf(M, mm[s]);
        }
        float L = 0.f, e[SPLIT];
        for (int s = 0; s < SPLIT; ++s) {
            e[s] = exp2f((mm[s] - M) * LOG2E);
            L += e[s] * llv[s];
        }
        float inv = 1.f / L;
        for (int s = 0; s < SPLIT; ++s) wl[s][t] = e[s] * llv[s] * inv;
    }
    __syncthreads();

    const float g = gamma_p[0];
    for (int rep = 0; rep < 4; ++rep) {
        int c = rep * 32 + (t >> 3), i8 = (t & 7) * 8;
        size_t base = ((size_t)b * CH + c) * NPIX + i0 + i8;
        float acc[8] = {0.f, 0.f, 0.f, 0.f, 0.f, 0.f, 0.f, 0.f};
        for (int s = 0; s < SPLIT; ++s) {
            half8 o = *(const half8*)(o_part +
                ((size_t)(s * BATCH + b) * CH + c) * NPIX + i0 + i8);
            for (int e = 0; e < 8; ++e) acc[e] += wl[s][i8 + e] * (float)o[e];
        }
        float sc = scale[b * 128 + c];
        float4 x0 = *(const float4*)(x + base);
        float4 x1 = *(const float4*)(x + base + 4);
        float4 r0, r1;
        r0.x = g * acc[0] + x0.x * sc; r0.y = g * acc[1] + x0.y * sc;
        r0.z = g * acc[2] + x0.z * sc; r0.w = g * acc[3] + x0.w * sc;
        r1.x = g * acc[4] + x1.x * sc; r1.y = g * acc[5] + x1.y * sc;
        r1.z = g * acc[6] + x1.z * sc; r1.w = g * acc[7] + x1.w * sc;
        *(float4*)(out + base) = r0;
        *(float4*)(out + base + 4) = r1;
    }
}

// ---------------- host launcher ----------------
extern "C" void kernel_launch(void* const* d_in, const int* in_sizes, int n_in,
                              void* d_out, int out_size, void* d_ws, size_t ws_size,
                              hipStream_t stream) {
    const float* x     = (const float*)d_in[0];
    const float* Wq    = (const float*)d_in[1];
    const float* bq    = (const float*)d_in[2];
    const float* Wk    = (const float*)d_in[3];
    const float* bk    = (const float*)d_in[4];
    const float* Wv    = (const float*)d_in[5];
    const float* bv    = (const float*)d_in[6];
    const float* se_w1 = (const float*)d_in[7];
    const float* se_w2 = (const float*)d_in[8];
    const float* gamma = (const float*)d_in[9];
    float* out = (float*)d_out;

    char* ws = (char*)d_ws;
    const size_t E = (size_t)BATCH * NPIX * CH;          // 2,359,296 elems
    _Float16* qT = (_Float16*)(ws);                      // E f16
    _Float16* kT = (_Float16*)(ws + E * 2);
    _Float16* vN = (_Float16*)(ws + E * 4);
    _Float16* op = (_Float16*)(ws + E * 6);              // SPLIT*E f16
    char* tail   = ws + E * 6 + (size_t)SPLIT * E * 2;
    _Float16* Wh = (_Float16*)(tail);                    // 49152 f16
    float* g_m   = (float*)(tail + 98304);
    float* g_l   = (float*)(tail + 98304 + SPLIT * BN * 4);
    float* y0    = (float*)(tail + 98304 + 2 * SPLIT * BN * 4);
    float* scale = (float*)(tail + 98304 + 2 * SPLIT * BN * 4 + 4096);

    k_prep<<<1216, 256, 0, stream>>>(x, Wq, Wk, Wv, Wh, y0);
    k_proj<<<dim3(NPIX / 128, BATCH, 4), 256, 0, stream>>>(
        x, Wh, bq, bk, bv, qT, kT, vN, y0, se_w1, se_w2, scale);
    k_attn<<<dim3(NPIX / 64, BATCH, SPLIT), 256, 0, stream>>>(
        qT, kT, vN, op, g_m, g_l);
    k_combine<<<dim3(NPIX / 64, BATCH), 256, 0, stream>>>(
        op, g_m, g_l, x, scale, gamma, out);
}

// Round 2
// 162.861 us; speedup vs baseline: 1.0576x; 1.0576x over previous
//
#include <hip/hip_runtime.h>

typedef _Float16 half8 __attribute__((ext_vector_type(8)));
typedef _Float16 half4 __attribute__((ext_vector_type(4)));
typedef float f32x4 __attribute__((ext_vector_type(4)));

#define BATCH 8
#define CH 128
#define NPIX 2304   // 48*48
#define SPLIT 4
#define JPER (NPIX / SPLIT)          // 576 = 9 tiles of 64
#define BN (BATCH * NPIX)
#define LOG2E 1.44269504088896f

__device__ __forceinline__ f32x4 mfma32(half8 a, half8 b, f32x4 c) {
    return __builtin_amdgcn_mfma_f32_16x16x32_f16(a, b, c, 0, 0, 0);
}
__device__ __forceinline__ f32x4 mfma16(half4 a, half4 b, f32x4 c) {
    return __builtin_amdgcn_mfma_f32_16x16x16f16(a, b, c, 0, 0, 0);
}

// async global->LDS, 16B per lane; LDS dest is wave-uniform base + lane*16
__device__ __forceinline__ void gl_lds16(const _Float16* g, _Float16* l) {
    typedef const __attribute__((address_space(1))) unsigned int gu32;
    typedef __attribute__((address_space(3))) unsigned int lu32;
    __builtin_amdgcn_global_load_lds((gu32*)g, (lu32*)l, 16, 0, 0);
}

// ---------------- prep: pool (blocks 0..1023), W convert (1024..1215) ----------------
__global__ __launch_bounds__(256) void k_prep(
        const float* __restrict__ x, const float* __restrict__ Wq,
        const float* __restrict__ Wk, const float* __restrict__ Wv,
        _Float16* __restrict__ Wh, float* __restrict__ y0) {
    const int bid = blockIdx.x;
    const int t = threadIdx.x;
    if (bid < 1024) {                        // ---- global average pool
        const int row = bid;                  // b*128 + c
        const float4* p = (const float4*)(x + (size_t)row * NPIX);
        float s = 0.f;
        for (int tt = t; tt < NPIX / 4; tt += 256) {
            float4 v = p[tt];
            s += v.x + v.y + v.z + v.w;
        }
        for (int m = 1; m < 64; m <<= 1) s += __shfl_xor(s, m);
        __shared__ float ls[4];
        if ((t & 63) == 0) ls[t >> 6] = s;
        __syncthreads();
        if (t == 0) y0[row] = (ls[0] + ls[1] + ls[2] + ls[3]) * (1.0f / (float)NPIX);
    } else {                                  // ---- W f32 -> f16
        int i = (bid - 1024) * 256 + t;       // 0..49151
        const float* src = (i < 16384) ? Wq : ((i < 32768) ? Wk : Wv);
        Wh[i] = (_Float16)src[i & 16383];
    }
}

// ---------------- QKV projection (x transposed in-LDS) + SE on z==3 ----------------
// grid (18, 8, 4); block 256. z: 0=q (B,N,C), 1=k (B,N,C), 2=v (B,C,N), 3=SE
__global__ __launch_bounds__(256) void k_proj(
        const float* __restrict__ x, const _Float16* __restrict__ Wh,
        const float* __restrict__ bq, const float* __restrict__ bk, const float* __restrict__ bv,
        _Float16* __restrict__ qT, _Float16* __restrict__ kT, _Float16* __restrict__ vN,
        const float* __restrict__ y0, const float* __restrict__ se_w1,
        const float* __restrict__ se_w2, float* __restrict__ scale) {
    const int which = blockIdx.z;
    const int t = threadIdx.x;

    if (which == 3) {                         // ---- SE MLP: 1 active block
        if (blockIdx.x != 0 || blockIdx.y != 0) return;
        __shared__ float ly[128];
        __shared__ float ly1[8];
        for (int b = 0; b < BATCH; ++b) {
            if (t < 128) ly[t] = y0[b * 128 + t];
            __syncthreads();
            if (t < 8) {
                float a = 0.f;
                for (int c = 0; c < 128; ++c) a += se_w1[t * 128 + c] * ly[c];
                ly1[t] = fmaxf(a, 0.f);
            }
            __syncthreads();
            if (t < 128) {
                float a = 0.f;
                for (int r = 0; r < 8; ++r) a += se_w2[t * 8 + r] * ly1[r];
                scale[b * 128 + t] = 1.f / (1.f + __expf(-a));
            }
            __syncthreads();
        }
        return;
    }

    const int n0 = blockIdx.x * 128;
    const int b = blockIdx.y;
    const float* bias = (which == 0) ? bq : ((which == 1) ? bk : bv);
    const _Float16* W = Wh + which * 16384;

    __shared__ __align__(16) _Float16 xt[128 * 128];  // swizzled [n][c]

    { // stage x tile: f32 (C-major) -> f16 transposed swizzled [n][c]
        const float* xb = x + (size_t)b * CH * NPIX + n0;
        for (int rep = 0; rep < 16; ++rep) {
            int flat = rep * 256 + t;
            int c = flat >> 5;                // 0..127
            int n4 = (flat & 31) * 4;         // 0..124
            float4 v4 = *(const float4*)(xb + (size_t)c * NPIX + n4);
            int cc = c & 7, ck = c >> 3;
            xt[(n4 + 0) * 128 + ((ck ^ ((n4 + 0) & 7)) * 8) + cc] = (_Float16)v4.x;
            xt[(n4 + 1) * 128 + ((ck ^ ((n4 + 1) & 7)) * 8) + cc] = (_Float16)v4.y;
            xt[(n4 + 2) * 128 + ((ck ^ ((n4 + 2) & 7)) * 8) + cc] = (_Float16)v4.z;
            xt[(n4 + 3) * 128 + ((ck ^ ((n4 + 3) & 7)) * 8) + cc] = (_Float16)v4.w;
        }
    }
    __syncthreads();

    const int lane = t & 63, w = t >> 6;
    const int ln15 = lane & 15, quad = lane >> 4;

    f32x4 zero4 = {0.f, 0.f, 0.f, 0.f};
    f32x4 acc[8][2];
    for (int mt = 0; mt < 8; ++mt) { acc[mt][0] = zero4; acc[mt][1] = zero4; }

    for (int ks = 0; ks < 4; ++ks) {
        half8 bf[2];
        for (int nt = 0; nt < 2; ++nt) {
            int row = w * 32 + nt * 16 + ln15;
            int ch = ks * 4 + quad;
            bf[nt] = *(const half8*)(xt + row * 128 + ((ch ^ (row & 7)) * 8));
        }
        for (int mt = 0; mt < 8; ++mt) {
            half8 af = *(const half8*)(W + (mt * 16 + ln15) * 128 + ks * 32 + quad * 8);
            acc[mt][0] = mfma32(af, bf[0], acc[mt][0]);
            acc[mt][1] = mfma32(af, bf[1], acc[mt][1]);
        }
    }
    __syncthreads();   // xt reuse as transpose buffer

    if (which == 2) {
        // [c][n] swizzled, then coalesced store to vN (B,C,N)
        for (int mt = 0; mt < 8; ++mt)
            for (int nt = 0; nt < 2; ++nt)
                for (int r = 0; r < 4; ++r) {
                    int c = mt * 16 + quad * 4 + r;
                    int nl = w * 32 + nt * 16 + ln15;
                    xt[c * 128 + (((nl >> 3) ^ (c & 7)) * 8) + (nl & 7)] =
                        (_Float16)(acc[mt][nt][r] + bias[c]);
                }
        __syncthreads();
        _Float16* vb = vN + (size_t)b * CH * NPIX + n0;
        for (int rep = 0; rep < 8; ++rep) {
            int c = rep * 16 + (t >> 4), ch = t & 15;
            *(half8*)(vb + (size_t)c * NPIX + ch * 8) =
                *(const half8*)(xt + c * 128 + ((ch ^ (c & 7)) * 8));
        }
    } else {
        // [n][c] swizzled, then coalesced store to qT/kT (B,N,C)
        for (int mt = 0; mt < 8; ++mt)
            for (int nt = 0; nt < 2; ++nt)
                for (int r = 0; r < 4; ++r) {
                    int c = mt * 16 + quad * 4 + r;
                    int nl = w * 32 + nt * 16 + ln15;
                    xt[nl * 128 + (((c >> 3) ^ (nl & 7)) * 8) + (c & 7)] =
                        (_Float16)(acc[mt][nt][r] + bias[c]);
                }
        __syncthreads();
        _Float16* dst = ((which == 0) ? qT : kT) + ((size_t)b * NPIX + n0) * CH;
        for (int rep = 0; rep < 8; ++rep) {
            int nl = rep * 16 + (t >> 4), ch = t & 15;
            *(half8*)(dst + nl * 128 + ch * 8) =
                *(const half8*)(xt + nl * 128 + ((ch ^ (nl & 7)) * 8));
        }
    }
}

// ---------------- flash attention: double-buffered async LDS staging ----------------
// grid (36, 8, SPLIT); block 256. Wave w owns i-rows i0+16w..+15; all waves share K/V tile.
// T3-lite: tile t+1 staged via global_load_lds (pre-swizzled SOURCE, linear dest — rule 21)
// while tile t computes; single __syncthreads per tile (its vmcnt(0) drain is the wanted
// depth-1 wait). T5: setprio around MFMA. T13: defer-max; o_part stored normalized by 1/l.
__global__ __launch_bounds__(256, 2) void k_attn(
        const _Float16* __restrict__ qT, const _Float16* __restrict__ kT,
        const _Float16* __restrict__ vN,
        _Float16* __restrict__ o_part, float* __restrict__ g_m, float* __restrict__ g_l) {
    const int i0 = blockIdx.x * 64;
    const int b = blockIdx.y;
    const int split = blockIdx.z;
    const int t = threadIdx.x;
    const int lane = t & 63, w = t >> 6;
    const int ln15 = lane & 15, quad = lane >> 4;

    // double buffer: buf = sh + cur*16384; K = buf[0..8192), V = buf[8192..16384)
    __shared__ __align__(16) _Float16 sh[32768];   // 64 KB

    // Q frags (B-operand of S^T): i = i0 + 16w + ln15
    half8 qf[4];
    {
        const _Float16* qb = qT + ((size_t)b * NPIX + i0 + w * 16 + ln15) * CH + quad * 8;
        for (int kc = 0; kc < 4; ++kc) qf[kc] = *(const half8*)(qb + kc * 32);
    }

    const _Float16* kb0 = kT + ((size_t)b * NPIX) * CH;
    const _Float16* vb0 = vN + (size_t)b * CH * NPIX;

    // stage one K/V tile into LDS buffer via global_load_lds.
    // K: LDS linear dest; lane L of issue (w,r) lands at elem (r*4+w)*512 + L*8
    //    => row = 4*(r*4+w) + (L>>4), chunk-slot p = L&15; source chunk = p ^ (row&7)
    //    (read side uses the same XOR involution -> data retrieved un-permuted)
    // V: lane L of issue (w,r): c = 8*(r*4+w) + (L>>3), slot p = L&7; source chunk = p^(c&7)
    auto stage = [&](int j0, _Float16* buf) {
        #pragma unroll
        for (int r = 0; r < 4; ++r) {
            int idx = r * 4 + w;
            int row = 4 * idx + (lane >> 4);
            int ch  = (lane & 15) ^ (row & 7);
            gl_lds16(kb0 + (size_t)(j0 + row) * CH + ch * 8,
                     buf + idx * 512);                 // wave-uniform LDS base
        }
        #pragma unroll
        for (int r = 0; r < 4; ++r) {
            int idx = r * 4 + w;
            int c  = 8 * idx + (lane >> 3);
            int ch = (lane & 7) ^ (c & 7);
            gl_lds16(vb0 + (size_t)c * NPIX + j0 + ch * 8,
                     buf + 8192 + idx * 512);          // wave-uniform LDS base
        }
    };

    // prologue: stage tile 0
    stage(split * JPER, sh);
    __syncthreads();   // vmcnt(0) drain: tile 0 landed

    f32x4 zero4 = {0.f, 0.f, 0.f, 0.f};
    f32x4 os[8];
    for (int ct = 0; ct < 8; ++ct) os[ct] = zero4;
    float m = -1e30f, l = 0.f;
    int cur = 0;

    for (int it = 0; it < 9; ++it) {
        _Float16* k_s = sh + cur * 16384;
        _Float16* v_s = k_s + 8192;

        // issue next tile's loads into the other buffer (in flight across compute)
        if (it < 8) stage(split * JPER + (it + 1) * 64, sh + (cur ^ 1) * 16384);

        // ---- S^T = K·Q^T : D[j = 16jt + quad*4+r][i = ln15]
        f32x4 s[4];
        for (int jt = 0; jt < 4; ++jt) s[jt] = zero4;
        __builtin_amdgcn_s_setprio(1);
        for (int jt = 0; jt < 4; ++jt) {
            for (int kc = 0; kc < 4; ++kc) {
                int row = jt * 16 + ln15, ch = kc * 4 + quad;
                half8 kf = *(const half8*)(k_s + row * 128 + ((ch ^ (row & 7)) * 8));
                s[jt] = mfma32(kf, qf[kc], s[jt]);
            }
        }
        __builtin_amdgcn_s_setprio(0);

        // ---- online softmax with deferred rescale (T13, THR=8)
        float mx = fmaxf(fmaxf(s[0][0], s[0][1]), fmaxf(s[0][2], s[0][3]));
        for (int jt = 1; jt < 4; ++jt)
            mx = fmaxf(mx, fmaxf(fmaxf(s[jt][0], s[jt][1]), fmaxf(s[jt][2], s[jt][3])));
        mx = fmaxf(mx, __shfl_xor(mx, 16));
        mx = fmaxf(mx, __shfl_xor(mx, 32));
        if (!__all(mx - m <= 8.0f)) {
            float mnew = fmaxf(m, mx);
            float alpha = exp2f((m - mnew) * LOG2E);
            for (int ct = 0; ct < 8; ++ct) {
                os[ct][0] *= alpha; os[ct][1] *= alpha;
                os[ct][2] *= alpha; os[ct][3] *= alpha;
            }
            l *= alpha;
            m = mnew;
        }
        float mbias = m * LOG2E;

        float sum = 0.f;
        half4 pf[4];
        for (int jt = 0; jt < 4; ++jt)
            for (int r = 0; r < 4; ++r) {
                float p = exp2f(fmaf(s[jt][r], LOG2E, -mbias));   // bounded by e^8
                sum += p;
                pf[jt][r] = (_Float16)p;
            }
        sum += __shfl_xor(sum, 16);
        sum += __shfl_xor(sum, 32);
        l += sum;

        // ---- O^T += V · P^T  (K=16 MFMA; P in registers, V from LDS)
        __builtin_amdgcn_s_setprio(1);
        for (int ct = 0; ct < 8; ++ct) {
            int c = ct * 16 + ln15;
            for (int jt = 0; jt < 4; ++jt) {
                int chunk = jt * 2 + (quad >> 1);
                half4 vf = *(const half4*)(v_s + c * 64 + ((chunk ^ (c & 7)) * 8) + (quad & 1) * 4);
                os[ct] = mfma16(vf, pf[jt], os[ct]);
            }
        }
        __builtin_amdgcn_s_setprio(0);

        // one barrier per tile: drains vmcnt(0) (next tile landed) and
        // guarantees all waves' LDS reads of this tile are done
        __syncthreads();
        cur ^= 1;
    }

    // ---- epilogue: m/l out; O^T normalized by 1/l, f16 via LDS transpose, coalesced store
    if (quad == 0) {
        int i = i0 + w * 16 + ln15;
        g_m[(size_t)(split * BATCH + b) * NPIX + i] = m;
        g_l[(size_t)(split * BATCH + b) * NPIX + i] = l;
    }
    const float linv = 1.0f / l;
    for (int ct = 0; ct < 8; ++ct)
        for (int r = 0; r < 4; ++r) {
            int c = ct * 16 + quad * 4 + r;
            int il = w * 16 + ln15;
            int chunk = (il >> 3);
            sh[c * 64 + ((chunk ^ (c & 7)) * 8) + (il & 7)] = (_Float16)(os[ct][r] * linv);
        }
    __syncthreads();
    _Float16* op = o_part + (size_t)(split * BATCH + b) * CH * NPIX;
    for (int rep = 0; rep < 4; ++rep) {
        int c = rep * 32 + (t >> 3), ch = t & 7;
        *(half8*)(op + (size_t)c * NPIX + i0 + ch * 8) =
            *(const half8*)(sh + c * 64 + ((ch ^ (c & 7)) * 8));
    }
}

// ---------------- combine (fused split-weights) + SE epilogue ----------------
// grid (36, 8); block 256. o_part is per-split NORMALIZED -> weight = e_s*l_s/L
__global__ __launch_bounds__(256) void k_combine(
        const _Float16* __restrict__ o_part, const float* __restrict__ g_m,
        const float* __restrict__ g_l, const float* __restrict__ x,
        const float* __restrict__ scale, const float* __restrict__ gamma_p,
        float* __restrict__ out) {
    const int i0 = blockIdx.x * 64;
    const int b = blockIdx.y;
    const int t = threadIdx.x;
    __shared__ float wl[SPLIT][64];

    if (t < 64) {
        int i = i0 + t;
        float mm[SPLIT], llv[SPLIT];
        float M = -1e30f;
        for (int s = 0; s < SPLIT; ++s) {
            mm[s] = g_m[(size_t)(s * BATCH + b) * NPIX + i];
            llv[s] = g_l[(size_t)(s * BATCH + b) * NPIX + i];
            M = fmaxf(M, mm[s]);
        }
        float L = 0.f, e[SPLIT];
        for (int s = 0; s < SPLIT; ++s) {
            e[s] = exp2f((mm[s] - M) * LOG2E);
            L += e[s] * llv[s];
        }
        float inv = 1.f / L;
        for (int s = 0; s < SPLIT; ++s) wl[s][t] = e[s] * llv[s] * inv;
    }
    __syncthreads();

    const float g = gamma_p[0];
    for (int rep = 0; rep < 4; ++rep) {
        int c = rep * 32 + (t >> 3), i8 = (t & 7) * 8;
        size_t base = ((size_t)b * CH + c) * NPIX + i0 + i8;
        float acc[8] = {0.f, 0.f, 0.f, 0.f, 0.f, 0.f, 0.f, 0.f};
        for (int s = 0; s < SPLIT; ++s) {
            half8 o = *(const half8*)(o_part +
                ((size_t)(s * BATCH + b) * CH + c) * NPIX + i0 + i8);
            for (int e = 0; e < 8; ++e) acc[e] += wl[s][i8 + e] * (float)o[e];
        }
        float sc = scale[b * 128 + c];
        float4 x0 = *(const float4*)(x + base);
        float4 x1 = *(const float4*)(x + base + 4);
        float4 r0, r1;
        r0.x = g * acc[0] + x0.x * sc; r0.y = g * acc[1] + x0.y * sc;
        r0.z = g * acc[2] + x0.z * sc; r0.w = g * acc[3] + x0.w * sc;
        r1.x = g * acc[4] + x1.x * sc; r1.y = g * acc[5] + x1.y * sc;
        r1.z = g * acc[6] + x1.z * sc; r1.w = g * acc[7] + x1.w * sc;
        *(float4*)(out + base) = r0;
        *(float4*)(out + base + 4) = r1;
    }
}

// ---------------- host launcher ----------------
extern "C" void kernel_launch(void* const* d_in, const int* in_sizes, int n_in,
                              void* d_out, int out_size, void* d_ws, size_t ws_size,
                              hipStream_t stream) {
    const float* x     = (const float*)d_in[0];
    const float* Wq    = (const float*)d_in[1];
    const float* bq    = (const float*)d_in[2];
    const float* Wk    = (const float*)d_in[3];
    const float* bk    = (const float*)d_in[4];
    const float* Wv    = (const float*)d_in[5];
    const float* bv    = (const float*)d_in[6];
    const float* se_w1 = (const float*)d_in[7];
    const float* se_w2 = (const float*)d_in[8];
    const float* gamma = (const float*)d_in[9];
    float* out = (float*)d_out;

    char* ws = (char*)d_ws;
    const size_t E = (size_t)BATCH * NPIX * CH;          // 2,359,296 elems
    _Float16* qT = (_Float16*)(ws);                      // E f16
    _Float16* kT = (_Float16*)(ws + E * 2);
    _Float16* vN = (_Float16*)(ws + E * 4);
    _Float16* op = (_Float16*)(ws + E * 6);              // SPLIT*E f16
    char* tail   = ws + E * 6 + (size_t)SPLIT * E * 2;
    _Float16* Wh = (_Float16*)(tail);                    // 49152 f16
    float* g_m   = (float*)(tail + 98304);
    float* g_l   = (float*)(tail + 98304 + SPLIT * BN * 4);
    float* y0    = (float*)(tail + 98304 + 2 * SPLIT * BN * 4);
    float* scale = (float*)(tail + 98304 + 2 * SPLIT * BN * 4 + 4096);

    k_prep<<<1216, 256, 0, stream>>>(x, Wq, Wk, Wv, Wh, y0);
    k_proj<<<dim3(NPIX / 128, BATCH, 4), 256, 0, stream>>>(
        x, Wh, bq, bk, bv, qT, kT, vN, y0, se_w1, se_w2, scale);
    k_attn<<<dim3(NPIX / 64, BATCH, SPLIT), 256, 0, stream>>>(
        qT, kT, vN, op, g_m, g_l);
    k_combine<<<dim3(NPIX / 64, BATCH), 256, 0, stream>>>(
        op, g_m, g_l, x, scale, gamma, out);
}